// Round 1
// baseline (408.543 us; speedup 1.0000x reference)
//
#include <hip/hip_runtime.h>
#include <cstdint>
#include <cstddef>

#define GLOBAL_AS __attribute__((address_space(1)))
#define LDS_AS __attribute__((address_space(3)))

typedef __attribute__((ext_vector_type(8))) short short8;
typedef __attribute__((ext_vector_type(4))) short short4v;
typedef __attribute__((ext_vector_type(4))) float floatx4;

static __device__ __forceinline__ unsigned short f2bf(float f) {
  uint32_t u = __builtin_bit_cast(uint32_t, f);
  u += 0x7fffu + ((u >> 16) & 1u);   // round-to-nearest-even
  return (unsigned short)(u >> 16);
}
static __device__ __forceinline__ float bf2f(unsigned short s) {
  return __builtin_bit_cast(float, (uint32_t)s << 16);
}

// ---------------------------------------------------------------------------
// Elementwise fp32 -> bf16 convert (vectorized x4)
// ---------------------------------------------------------------------------
__global__ __launch_bounds__(256) void cvt_bf16_kernel(
    const float* __restrict__ in, unsigned short* __restrict__ out, int n4) {
  int i = blockIdx.x * 256 + threadIdx.x;
  if (i < n4) {
    const float4 v = ((const float4*)in)[i];
    short4v o;
    o.x = (short)f2bf(v.x);
    o.y = (short)f2bf(v.y);
    o.z = (short)f2bf(v.z);
    o.w = (short)f2bf(v.w);
    ((short4v*)out)[i] = o;
  }
}

// ---------------------------------------------------------------------------
// Tiled transpose + convert: in fp32 [R][C] -> out bf16 [C][R]
// 64x64 tile, LDS padded to kill bank conflicts. grid = (C/64, R/64)
// ---------------------------------------------------------------------------
__global__ __launch_bounds__(256) void transpose_bf16_kernel(
    const float* __restrict__ in, unsigned short* __restrict__ out, int R, int C) {
  __shared__ float t[64][65];
  const int bc = blockIdx.x * 64;
  const int br = blockIdx.y * 64;
  const int tc = threadIdx.x & 63;
  const int tr = threadIdx.x >> 6;
  for (int r = tr; r < 64; r += 4)
    t[r][tc] = in[(size_t)(br + r) * C + bc + tc];
  __syncthreads();
  for (int r = tr; r < 64; r += 4)
    out[(size_t)(bc + r) * R + br + tc] = f2bf(t[tc][r]);
}

// ---------------------------------------------------------------------------
// Row-sum of bf16 matrix P [rows][ncols] -> l[row0+row] (fp32)
// one block per row, 16B vector loads
// ---------------------------------------------------------------------------
__global__ __launch_bounds__(256) void rowsum_kernel(
    const unsigned short* __restrict__ P, float* __restrict__ l, int ncols, int row0) {
  const int row = blockIdx.x;
  const unsigned short* p = P + (size_t)row * ncols;
  float s = 0.f;
  for (int c = threadIdx.x * 8; c < ncols; c += 256 * 8) {
    short8 v = *(const short8*)(p + c);
#pragma unroll
    for (int k = 0; k < 8; ++k) s += bf2f((unsigned short)v[k]);
  }
#pragma unroll
  for (int off = 32; off > 0; off >>= 1) s += __shfl_down(s, off);
  __shared__ float red[4];
  if ((threadIdx.x & 63) == 0) red[threadIdx.x >> 6] = s;
  __syncthreads();
  if (threadIdx.x == 0) l[row0 + row] = red[0] + red[1] + red[2] + red[3];
}

// ---------------------------------------------------------------------------
// bf16 GEMM, B-transposed form: C[m][n] = sum_k A[m][k] * Bt[n][k]
// m97 structure: 128x128 tile, BK=32, 256 threads (4 waves, 2x2 of 64x64),
// 16x16x32 bf16 MFMA (4x4 tiles/wave), global_load_lds width=16 staging.
// MODE 0: C = A*B + bias  -> bf16 Cb            (Q/K projection)
// MODE 1: C = exp(diag0(A*B)*scale) -> bf16 Cb  (scores -> P)
// MODE 2: C = A*B / l[row] + Hres    -> fp32 Cf (PV + residual)
// All dims multiples of 128 (M via grid), K multiple of 32. No bounds checks.
// ---------------------------------------------------------------------------
template <int MODE>
__global__ __launch_bounds__(256, 2) void gemm_bt(
    const unsigned short* __restrict__ A,    // [M][K] bf16 (row-chunk base)
    const unsigned short* __restrict__ Bt,   // [Ncols][K] bf16
    int Ncols, int K,
    const float* __restrict__ bias,          // MODE0: [Ncols]
    const float* __restrict__ lvec,          // MODE2: l[global row]
    const float* __restrict__ Hres,          // MODE2: H fp32 [N][512]
    int row0,                                // global row offset of this chunk
    unsigned short* __restrict__ Cb,         // MODE0/1 out (chunk-local rows)
    float* __restrict__ Cf)                  // MODE2 out (global rows)
{
  __shared__ unsigned short As[128 * 32];    // 8 KiB
  __shared__ unsigned short Bs[128 * 32];    // 8 KiB

  const int tid  = threadIdx.x;
  const int lane = tid & 63;
  const int wave = tid >> 6;
  const int wr   = (wave >> 1) * 64;         // wave row offset in 128x128 tile
  const int wc   = (wave & 1) * 64;          // wave col offset
  const int quad = lane >> 4;
  const int l15  = lane & 15;
  const int bm   = blockIdx.y * 128;
  const int bn   = blockIdx.x * 128;

  floatx4 acc[4][4];
#pragma unroll
  for (int i = 0; i < 4; ++i)
#pragma unroll
    for (int j = 0; j < 4; ++j)
      acc[i][j] = (floatx4){0.f, 0.f, 0.f, 0.f};

  // staging map: chunk c (16B = 8 bf16) covers row c>>2, k-offset (c&3)*8;
  // LDS linear offset = c*8 elems -> wave-uniform base + lane*16B as required.
  const int c0 = tid, c1 = tid + 256;
  const int r0a = c0 >> 2, k0a = (c0 & 3) << 3;
  const int r1a = c1 >> 2, k1a = (c1 & 3) << 3;

  for (int kt = 0; kt < K; kt += 32) {
    __builtin_amdgcn_global_load_lds(
        (const GLOBAL_AS void*)(A + (size_t)(bm + r0a) * K + kt + k0a),
        (LDS_AS void*)(As + c0 * 8), 16, 0, 0);
    __builtin_amdgcn_global_load_lds(
        (const GLOBAL_AS void*)(A + (size_t)(bm + r1a) * K + kt + k1a),
        (LDS_AS void*)(As + c1 * 8), 16, 0, 0);
    __builtin_amdgcn_global_load_lds(
        (const GLOBAL_AS void*)(Bt + (size_t)(bn + r0a) * K + kt + k0a),
        (LDS_AS void*)(Bs + c0 * 8), 16, 0, 0);
    __builtin_amdgcn_global_load_lds(
        (const GLOBAL_AS void*)(Bt + (size_t)(bn + r1a) * K + kt + k1a),
        (LDS_AS void*)(Bs + c1 * 8), 16, 0, 0);
    __syncthreads();

    short8 af[4], bfr[4];
#pragma unroll
    for (int i = 0; i < 4; ++i)
      af[i] = *(const short8*)(As + (wr + i * 16 + l15) * 32 + quad * 8);
#pragma unroll
    for (int j = 0; j < 4; ++j)
      bfr[j] = *(const short8*)(Bs + (wc + j * 16 + l15) * 32 + quad * 8);
#pragma unroll
    for (int i = 0; i < 4; ++i)
#pragma unroll
      for (int j = 0; j < 4; ++j)
        acc[i][j] = __builtin_amdgcn_mfma_f32_16x16x32_bf16(af[i], bfr[j], acc[i][j], 0, 0, 0);
    __syncthreads();
  }

  // epilogue — C/D layout (verified m89): col = lane&15, row = quad*4 + reg
  const float scale = 0.044194173824159216f;  // 1/sqrt(512)
#pragma unroll
  for (int i = 0; i < 4; ++i) {
    const int rl = bm + wr + i * 16 + quad * 4;
#pragma unroll
    for (int j = 0; j < 4; ++j) {
      const int col = bn + wc + j * 16 + l15;
#pragma unroll
      for (int r = 0; r < 4; ++r) {
        const int row = rl + r;
        const float v = acc[i][j][r];
        if (MODE == 0) {
          Cb[(size_t)row * Ncols + col] = f2bf(v + bias[col]);
        } else if (MODE == 1) {
          const float lg = ((row0 + row) == col) ? 0.f : v * scale;
          Cb[(size_t)row * Ncols + col] = f2bf(__expf(lg));
        } else {
          const int grow = row0 + row;
          Cf[(size_t)grow * 512 + col] =
              v / lvec[grow] + Hres[(size_t)grow * 512 + col];
        }
      }
    }
  }
}

// ---------------------------------------------------------------------------
extern "C" void kernel_launch(void* const* d_in, const int* in_sizes, int n_in,
                              void* d_out, int out_size, void* d_ws, size_t ws_size,
                              hipStream_t stream) {
  const float* H  = (const float*)d_in[0];
  const float* Wq = (const float*)d_in[1];
  const float* bq = (const float*)d_in[2];
  const float* Wk = (const float*)d_in[3];
  const float* bk = (const float*)d_in[4];
  float* out = (float*)d_out;

  const int N = 8192, D = 512;

  char* ws = (char*)d_ws;
  size_t off = 0;
  auto alloc = [&](size_t bytes) { char* p = ws + off; off += bytes; return p; };
  unsigned short* Hb  = (unsigned short*)alloc((size_t)N * D * 2);
  unsigned short* HbT = (unsigned short*)alloc((size_t)N * D * 2);
  unsigned short* Qb  = (unsigned short*)alloc((size_t)N * D * 2);
  unsigned short* Kb  = (unsigned short*)alloc((size_t)N * D * 2);
  unsigned short* WqT = (unsigned short*)alloc((size_t)D * D * 2);
  unsigned short* WkT = (unsigned short*)alloc((size_t)D * D * 2);
  float* l = (float*)alloc((size_t)N * 4);
  const size_t base = off;
  unsigned short* P = (unsigned short*)(ws + base);

  // P row-chunking to fit whatever ws_size we got (full P = 134 MiB)
  const size_t rowBytes = (size_t)N * 2;
  size_t pavail = (ws_size > base) ? (ws_size - base) : 0;
  int maxRows = (int)(pavail / rowBytes);
  maxRows &= ~127;
  if (maxRows > N) maxRows = N;
  if (maxRows < 128) maxRows = 128;  // last-resort; assumes ws >= ~37 MiB

  // --- prep: bf16 copies / transposes ---
  cvt_bf16_kernel<<<dim3((N * D / 4 + 255) / 256), dim3(256), 0, stream>>>(H, Hb, N * D / 4);
  transpose_bf16_kernel<<<dim3(D / 64, N / 64), dim3(256), 0, stream>>>(H, HbT, N, D);
  transpose_bf16_kernel<<<dim3(D / 64, D / 64), dim3(256), 0, stream>>>(Wq, WqT, D, D);
  transpose_bf16_kernel<<<dim3(D / 64, D / 64), dim3(256), 0, stream>>>(Wk, WkT, D, D);

  // --- Q/K projections: [8192x512] = Hb @ W + b ---
  gemm_bt<0><<<dim3(D / 128, N / 128), dim3(256), 0, stream>>>(
      Hb, WqT, D, D, bq, nullptr, nullptr, 0, Qb, nullptr);
  gemm_bt<0><<<dim3(D / 128, N / 128), dim3(256), 0, stream>>>(
      Hb, WkT, D, D, bk, nullptr, nullptr, 0, Kb, nullptr);

  // --- attention, chunked over P rows ---
  for (int r0 = 0; r0 < N; r0 += maxRows) {
    int rows = N - r0;
    if (rows > maxRows) rows = maxRows;
    // P = exp(diag0(Q K^T) * scale)  [rows][8192] bf16
    gemm_bt<1><<<dim3(N / 128, rows / 128), dim3(256), 0, stream>>>(
        Qb + (size_t)r0 * D, Kb, N, D, nullptr, nullptr, nullptr, r0, P, nullptr);
    // l[r0..] = row sums of P
    rowsum_kernel<<<dim3(rows), dim3(256), 0, stream>>>(P, l, N, r0);
    // out rows = P @ H / l + H
    gemm_bt<2><<<dim3(D / 128, rows / 128), dim3(256), 0, stream>>>(
        P, HbT, D, N, nullptr, l, H, r0, nullptr, out);
  }
}

// Round 2
// 390.893 us; speedup vs baseline: 1.0452x; 1.0452x over previous
//
#include <hip/hip_runtime.h>
#include <cstdint>
#include <cstddef>

#define GLOBAL_AS __attribute__((address_space(1)))
#define LDS_AS __attribute__((address_space(3)))

typedef __attribute__((ext_vector_type(8))) short short8;
typedef __attribute__((ext_vector_type(4))) float floatx4;

static __device__ __forceinline__ unsigned short f2bf(float f) {
  uint32_t u = __builtin_bit_cast(uint32_t, f);
  u += 0x7fffu + ((u >> 16) & 1u);   // round-to-nearest-even
  return (unsigned short)(u >> 16);
}
static __device__ __forceinline__ float bf2f(unsigned short s) {
  return __builtin_bit_cast(float, (uint32_t)s << 16);
}

// ---------------------------------------------------------------------------
// Tiled transpose + convert: in fp32 [R][C] -> outT bf16 [C][R]
// optionally also writes straight-through bf16 copy outN [R][C].
// ---------------------------------------------------------------------------
__global__ __launch_bounds__(256) void transpose_bf16_kernel(
    const float* __restrict__ in, unsigned short* __restrict__ outT,
    unsigned short* __restrict__ outN, int R, int C) {
  __shared__ float t[64][65];
  const int bc = blockIdx.x * 64;
  const int br = blockIdx.y * 64;
  const int tc = threadIdx.x & 63;
  const int tr = threadIdx.x >> 6;
  for (int r = tr; r < 64; r += 4) {
    const float v = in[(size_t)(br + r) * C + bc + tc];
    t[r][tc] = v;
    if (outN) outN[(size_t)(br + r) * C + bc + tc] = f2bf(v);
  }
  __syncthreads();
  for (int r = tr; r < 64; r += 4)
    outT[(size_t)(bc + r) * R + br + tc] = f2bf(t[tc][r]);
}

// pack bqk = [bq ; bk]
__global__ __launch_bounds__(256) void pack_bias_kernel(
    const float* __restrict__ bq, const float* __restrict__ bk,
    float* __restrict__ bqk) {
  int i = blockIdx.x * 256 + threadIdx.x;
  bqk[i] = (i < 512) ? bq[i] : bk[i - 512];
}

// ---------------------------------------------------------------------------
// bf16 GEMM, B-transposed form: C[m][n] = sum_k A[m][k] * Bt[n][k]
// 128x128 tile, BK=32, 256 threads, 16x16x32 MFMA, global_load_lds staging.
// MODE 0: C = A*B + bias -> bf16                     (merged Q|K projection)
// MODE 1: C = exp(diag0(A*B)*scale) -> bf16, and atomic row-sums into lsum
// ---------------------------------------------------------------------------
template <int MODE>
__global__ __launch_bounds__(256, 2) void gemm_bt(
    const unsigned short* __restrict__ A,    // [M][lda] bf16
    const unsigned short* __restrict__ Bt,   // [Ncols][ldb] bf16
    int Ncols, int K, int lda, int ldb,
    const float* __restrict__ bias,          // MODE0
    float* __restrict__ lsum,                // MODE1: row-sum accumulator
    int row0,                                // global row offset of chunk
    unsigned short* __restrict__ Cb)
{
  __shared__ unsigned short As[128 * 32];
  __shared__ unsigned short Bs[128 * 32];

  const int tid  = threadIdx.x;
  const int lane = tid & 63;
  const int wave = tid >> 6;
  const int wr   = (wave >> 1) * 64;
  const int wc   = (wave & 1) * 64;
  const int quad = lane >> 4;
  const int l15  = lane & 15;
  const int bm   = blockIdx.y * 128;
  const int bn   = blockIdx.x * 128;

  floatx4 acc[4][4];
#pragma unroll
  for (int i = 0; i < 4; ++i)
#pragma unroll
    for (int j = 0; j < 4; ++j)
      acc[i][j] = (floatx4){0.f, 0.f, 0.f, 0.f};

  const int c0 = tid, c1 = tid + 256;
  const int r0a = c0 >> 2, k0a = (c0 & 3) << 3;
  const int r1a = c1 >> 2, k1a = (c1 & 3) << 3;

  for (int kt = 0; kt < K; kt += 32) {
    __builtin_amdgcn_global_load_lds(
        (const GLOBAL_AS void*)(A + (size_t)(bm + r0a) * lda + kt + k0a),
        (LDS_AS void*)(As + c0 * 8), 16, 0, 0);
    __builtin_amdgcn_global_load_lds(
        (const GLOBAL_AS void*)(A + (size_t)(bm + r1a) * lda + kt + k1a),
        (LDS_AS void*)(As + c1 * 8), 16, 0, 0);
    __builtin_amdgcn_global_load_lds(
        (const GLOBAL_AS void*)(Bt + (size_t)(bn + r0a) * ldb + kt + k0a),
        (LDS_AS void*)(Bs + c0 * 8), 16, 0, 0);
    __builtin_amdgcn_global_load_lds(
        (const GLOBAL_AS void*)(Bt + (size_t)(bn + r1a) * ldb + kt + k1a),
        (LDS_AS void*)(Bs + c1 * 8), 16, 0, 0);
    __syncthreads();

    short8 af[4], bfr[4];
#pragma unroll
    for (int i = 0; i < 4; ++i)
      af[i] = *(const short8*)(As + (wr + i * 16 + l15) * 32 + quad * 8);
#pragma unroll
    for (int j = 0; j < 4; ++j)
      bfr[j] = *(const short8*)(Bs + (wc + j * 16 + l15) * 32 + quad * 8);
#pragma unroll
    for (int i = 0; i < 4; ++i)
#pragma unroll
      for (int j = 0; j < 4; ++j)
        acc[i][j] = __builtin_amdgcn_mfma_f32_16x16x32_bf16(af[i], bfr[j], acc[i][j], 0, 0, 0);
    __syncthreads();
  }

  // epilogue — C/D layout: col = lane&15, row = quad*4 + reg
  const float scale = 0.044194173824159216f;  // 1/sqrt(512)
#pragma unroll
  for (int i = 0; i < 4; ++i) {
    const int rl = bm + wr + i * 16 + quad * 4;
#pragma unroll
    for (int r = 0; r < 4; ++r) {
      const int row = rl + r;
      float rsum = 0.f;
#pragma unroll
      for (int j = 0; j < 4; ++j) {
        const int col = bn + wc + j * 16 + l15;
        const float v = acc[i][j][r];
        if (MODE == 0) {
          Cb[(size_t)row * Ncols + col] = f2bf(v + bias[col]);
        } else {
          const float lg = ((row0 + row) == col) ? 0.f : v * scale;
          const unsigned short b = f2bf(__expf(lg));
          Cb[(size_t)row * Ncols + col] = b;
          rsum += bf2f(b);   // sum the ROUNDED value for num/denom consistency
        }
      }
      if (MODE == 1) {
        // reduce across the 16 lanes (l15) that share this row
        rsum += __shfl_xor(rsum, 1);
        rsum += __shfl_xor(rsum, 2);
        rsum += __shfl_xor(rsum, 4);
        rsum += __shfl_xor(rsum, 8);
        if (l15 == 0) atomicAdd(&lsum[row0 + row], rsum);
      }
    }
  }
}

// ---------------------------------------------------------------------------
// PV GEMM: O[m][n] = sum_k P[m][k] * HbT[n][k], 64x128 tile, split-K over z.
// DIRECT: writes out = v/l + H (single pass). Else writes fp32 partials.
// grid (ncols/128, rows/64, S); Kchunk = K/S.
// ---------------------------------------------------------------------------
template <bool DIRECT>
__global__ __launch_bounds__(256, 4) void gemm_pv(
    const unsigned short* __restrict__ P,    // [rows][8192] bf16 (chunk base)
    const unsigned short* __restrict__ Bt,   // HbT [512][8192] bf16
    int Kchunk,
    const float* __restrict__ lvec,
    const float* __restrict__ Hres,
    int row0,
    float* __restrict__ outp,                // DIRECT: out; else partials base
    size_t partStride)                       // floats per partial buffer
{
  __shared__ unsigned short As[64 * 32];     // 4 KiB
  __shared__ unsigned short Bs[128 * 32];    // 8 KiB

  const int tid  = threadIdx.x;
  const int lane = tid & 63;
  const int wave = tid >> 6;
  const int wr   = (wave >> 1) * 32;
  const int wc   = (wave & 1) * 64;
  const int quad = lane >> 4;
  const int l15  = lane & 15;
  const int bm   = blockIdx.y * 64;
  const int bn   = blockIdx.x * 128;
  const int k0   = blockIdx.z * Kchunk;

  float* part = outp + (DIRECT ? 0 : (size_t)blockIdx.z * partStride);

  floatx4 acc[2][4];
#pragma unroll
  for (int i = 0; i < 2; ++i)
#pragma unroll
    for (int j = 0; j < 4; ++j)
      acc[i][j] = (floatx4){0.f, 0.f, 0.f, 0.f};

  const int rA = tid >> 2, kA = (tid & 3) << 3;       // 256 chunks cover 64x32
  const int cB0 = tid, cB1 = tid + 256;               // 512 chunks cover 128x32
  const int rB0 = cB0 >> 2, kB0 = (cB0 & 3) << 3;
  const int rB1 = cB1 >> 2, kB1 = (cB1 & 3) << 3;

  for (int kt = k0; kt < k0 + Kchunk; kt += 32) {
    __builtin_amdgcn_global_load_lds(
        (const GLOBAL_AS void*)(P + (size_t)(bm + rA) * 8192 + kt + kA),
        (LDS_AS void*)(As + tid * 8), 16, 0, 0);
    __builtin_amdgcn_global_load_lds(
        (const GLOBAL_AS void*)(Bt + (size_t)(bn + rB0) * 8192 + kt + kB0),
        (LDS_AS void*)(Bs + cB0 * 8), 16, 0, 0);
    __builtin_amdgcn_global_load_lds(
        (const GLOBAL_AS void*)(Bt + (size_t)(bn + rB1) * 8192 + kt + kB1),
        (LDS_AS void*)(Bs + cB1 * 8), 16, 0, 0);
    __syncthreads();

    short8 af[2], bfr[4];
#pragma unroll
    for (int i = 0; i < 2; ++i)
      af[i] = *(const short8*)(As + (wr + i * 16 + l15) * 32 + quad * 8);
#pragma unroll
    for (int j = 0; j < 4; ++j)
      bfr[j] = *(const short8*)(Bs + (wc + j * 16 + l15) * 32 + quad * 8);
#pragma unroll
    for (int i = 0; i < 2; ++i)
#pragma unroll
      for (int j = 0; j < 4; ++j)
        acc[i][j] = __builtin_amdgcn_mfma_f32_16x16x32_bf16(af[i], bfr[j], acc[i][j], 0, 0, 0);
    __syncthreads();
  }

#pragma unroll
  for (int i = 0; i < 2; ++i) {
    const int rl = bm + wr + i * 16 + quad * 4;
#pragma unroll
    for (int j = 0; j < 4; ++j) {
      const int col = bn + wc + j * 16 + l15;
#pragma unroll
      for (int r = 0; r < 4; ++r) {
        const int row = rl + r;
        const float v = acc[i][j][r];
        if (DIRECT) {
          const int grow = row0 + row;
          part[(size_t)grow * 512 + col] =
              v / lvec[grow] + Hres[(size_t)grow * 512 + col];
        } else {
          part[(size_t)row * 512 + col] = v;
        }
      }
    }
  }
}

// combine: out = (sum_s partial_s) / l[row] + H
__global__ __launch_bounds__(256) void combine_kernel(
    const float* __restrict__ parts, size_t partStride, int S,
    const float* __restrict__ lvec, const float* __restrict__ Hres,
    float* __restrict__ out, int n4) {
  int i = blockIdx.x * 256 + threadIdx.x;
  if (i >= n4) return;
  float4 a = ((const float4*)parts)[i];
  for (int s = 1; s < S; ++s) {
    const float4 b = ((const float4*)(parts + (size_t)s * partStride))[i];
    a.x += b.x; a.y += b.y; a.z += b.z; a.w += b.w;
  }
  const int row = i >> 7;  // 128 float4 per 512-col row
  const float inv = 1.f / lvec[row];
  const float4 h = ((const float4*)Hres)[i];
  float4 o;
  o.x = a.x * inv + h.x;
  o.y = a.y * inv + h.y;
  o.z = a.z * inv + h.z;
  o.w = a.w * inv + h.w;
  ((float4*)out)[i] = o;
}

// ---------------------------------------------------------------------------
extern "C" void kernel_launch(void* const* d_in, const int* in_sizes, int n_in,
                              void* d_out, int out_size, void* d_ws, size_t ws_size,
                              hipStream_t stream) {
  const float* H  = (const float*)d_in[0];
  const float* Wq = (const float*)d_in[1];
  const float* bq = (const float*)d_in[2];
  const float* Wk = (const float*)d_in[3];
  const float* bk = (const float*)d_in[4];
  float* out = (float*)d_out;

  const int N = 8192, D = 512;

  char* ws = (char*)d_ws;
  size_t off = 0;
  auto alloc = [&](size_t bytes) { char* p = ws + off; off += bytes; return p; };
  unsigned short* Hb   = (unsigned short*)alloc((size_t)N * D * 2);       // 8 MB
  unsigned short* HbT  = (unsigned short*)alloc((size_t)N * D * 2);       // 8 MB
  unsigned short* QKb  = (unsigned short*)alloc((size_t)N * 2 * D * 2);   // 16.8 MB
  unsigned short* BqkT = (unsigned short*)alloc((size_t)2 * D * D * 2);   // 1 MB
  float* bqk = (float*)alloc((size_t)2 * D * 4);
  float* l   = (float*)alloc((size_t)N * 4);
  const size_t base = off;
  unsigned short* P = (unsigned short*)(ws + base);

  const size_t pBytes = (size_t)N * N * 2;               // 134 MB
  const size_t partBytes = (size_t)N * D * 4;            // 16.8 MB each
  const size_t partStride = (size_t)N * D;               // floats
  const size_t avail = (ws_size > base) ? (ws_size - base) : 0;

  int S = 0;  // 0 => must chunk P
  if (avail >= pBytes) {
    const size_t extra = avail - pBytes;
    S = (extra >= 4 * partBytes) ? 4 : (extra >= 2 * partBytes) ? 2 : 1;
  }
  float* parts = (float*)(ws + base + pBytes);

  // --- prep ---
  hipMemsetAsync(l, 0, (size_t)N * 4, stream);
  transpose_bf16_kernel<<<dim3(D / 64, N / 64), 256, 0, stream>>>(H, HbT, Hb, N, D);
  transpose_bf16_kernel<<<dim3(D / 64, D / 64), 256, 0, stream>>>(Wq, BqkT, nullptr, D, D);
  transpose_bf16_kernel<<<dim3(D / 64, D / 64), 256, 0, stream>>>(Wk, BqkT + (size_t)D * D, nullptr, D, D);
  pack_bias_kernel<<<dim3(4), 256, 0, stream>>>(bq, bk, bqk);

  // --- merged Q|K projection: QKb[8192][1024] = Hb @ [Wq|Wk] + [bq|bk] ---
  gemm_bt<0><<<dim3(2 * D / 128, N / 128), 256, 0, stream>>>(
      Hb, BqkT, 2 * D, D, D, D, bqk, nullptr, 0, QKb);

  if (S >= 1) {
    // scores: P = exp(diag0(Q K^T)*scale), fused row-sums into l
    gemm_bt<1><<<dim3(N / 128, N / 128), 256, 0, stream>>>(
        QKb, QKb + D, N, D, 2 * D, 2 * D, nullptr, l, 0, P);
    if (S == 1) {
      gemm_pv<true><<<dim3(D / 128, N / 64, 1), 256, 0, stream>>>(
          P, HbT, N, l, H, 0, out, 0);
    } else {
      gemm_pv<false><<<dim3(D / 128, N / 64, S), 256, 0, stream>>>(
          P, HbT, N / S, nullptr, nullptr, 0, parts, partStride);
      combine_kernel<<<dim3((N * D / 4 + 255) / 256), 256, 0, stream>>>(
          parts, partStride, S, l, H, out, N * D / 4);
    }
  } else {
    // ws too small for full P: chunk rows (direct PV per chunk)
    int maxRows = (int)(avail / ((size_t)N * 2));
    maxRows &= ~127;
    if (maxRows < 128) maxRows = 128;
    for (int r0 = 0; r0 < N; r0 += maxRows) {
      int rows = N - r0;
      if (rows > maxRows) rows = maxRows;
      gemm_bt<1><<<dim3(N / 128, rows / 128), 256, 0, stream>>>(
          QKb + (size_t)r0 * 2 * D, QKb + D, N, D, 2 * D, 2 * D, nullptr, l, r0, P);
      gemm_pv<true><<<dim3(D / 128, rows / 64, 1), 256, 0, stream>>>(
          P, HbT, N, l, H, r0, out, 0);
    }
  }
}

// Round 3
// 373.653 us; speedup vs baseline: 1.0934x; 1.0461x over previous
//
#include <hip/hip_runtime.h>
#include <cstdint>
#include <cstddef>

#define GLOBAL_AS __attribute__((address_space(1)))
#define LDS_AS __attribute__((address_space(3)))

typedef __attribute__((ext_vector_type(8))) short short8;
typedef __attribute__((ext_vector_type(4))) float floatx4;

static __device__ __forceinline__ unsigned short f2bf(float f) {
  uint32_t u = __builtin_bit_cast(uint32_t, f);
  u += 0x7fffu + ((u >> 16) & 1u);   // round-to-nearest-even
  return (unsigned short)(u >> 16);
}
static __device__ __forceinline__ float bf2f(unsigned short s) {
  return __builtin_bit_cast(float, (uint32_t)s << 16);
}

// ---------------------------------------------------------------------------
// Tiled transpose + convert: in fp32 [R][C] -> outT bf16 [C][R]
// optionally also writes straight-through bf16 copy outN [R][C].
// ---------------------------------------------------------------------------
__global__ __launch_bounds__(256) void transpose_bf16_kernel(
    const float* __restrict__ in, unsigned short* __restrict__ outT,
    unsigned short* __restrict__ outN, int R, int C) {
  __shared__ float t[64][65];
  const int bc = blockIdx.x * 64;
  const int br = blockIdx.y * 64;
  const int tc = threadIdx.x & 63;
  const int tr = threadIdx.x >> 6;
  for (int r = tr; r < 64; r += 4) {
    const float v = in[(size_t)(br + r) * C + bc + tc];
    t[r][tc] = v;
    if (outN) outN[(size_t)(br + r) * C + bc + tc] = f2bf(v);
  }
  __syncthreads();
  for (int r = tr; r < 64; r += 4)
    outT[(size_t)(bc + r) * R + br + tc] = f2bf(t[tc][r]);
}

// pack bqk = [bq ; bk]
__global__ __launch_bounds__(256) void pack_bias_kernel(
    const float* __restrict__ bq, const float* __restrict__ bk,
    float* __restrict__ bqk) {
  int i = blockIdx.x * 256 + threadIdx.x;
  bqk[i] = (i < 512) ? bq[i] : bk[i - 512];
}

// LDS k-block XOR swizzle: chunk c (16B) holds global (row=c>>2,
// kblock=(c^(c>>2))&3) at LDS linear c*16B. Reader for (row, q) uses
// chunk row*4 + ((q^row)&3). Drops fragment-read conflicts 8-way -> 4-way
// while keeping the global_load_lds wave-contiguous write requirement.
static __device__ __forceinline__ int swz(int c) { return (c ^ (c >> 2)) & 3; }

// ---------------------------------------------------------------------------
// bf16 GEMM, B-transposed form: C[m][n] = sum_k A[m][k] * Bt[n][k]
// 128x128 tile, BK=32, 256 threads, 16x16x32 MFMA, global_load_lds staging.
// MODE 0: C = A*B + bias -> bf16                     (merged Q|K projection)
// MODE 1: C = exp(diag0(A*B)*scale) -> bf16, and atomic row-sums into lsum
// ---------------------------------------------------------------------------
template <int MODE>
__global__ __launch_bounds__(256, 4) void gemm_bt(
    const unsigned short* __restrict__ A,    // [M][lda] bf16
    const unsigned short* __restrict__ Bt,   // [Ncols][ldb] bf16
    int Ncols, int K, int lda, int ldb,
    const float* __restrict__ bias,          // MODE0
    float* __restrict__ lsum,                // MODE1: row-sum accumulator
    int row0,                                // global row offset of chunk
    unsigned short* __restrict__ Cb)
{
  __shared__ unsigned short As[128 * 32];
  __shared__ unsigned short Bs[128 * 32];

  const int tid  = threadIdx.x;
  const int lane = tid & 63;
  const int wave = tid >> 6;
  const int wr   = (wave >> 1) * 64;
  const int wc   = (wave & 1) * 64;
  const int quad = lane >> 4;
  const int l15  = lane & 15;
  const int bm   = blockIdx.y * 128;
  const int bn   = blockIdx.x * 128;

  floatx4 acc[4][4];
#pragma unroll
  for (int i = 0; i < 4; ++i)
#pragma unroll
    for (int j = 0; j < 4; ++j)
      acc[i][j] = (floatx4){0.f, 0.f, 0.f, 0.f};

  const int c0 = tid, c1 = tid + 256;
  const int r0a = c0 >> 2, k0a = swz(c0) << 3;
  const int r1a = c1 >> 2, k1a = swz(c1) << 3;

  for (int kt = 0; kt < K; kt += 32) {
    __builtin_amdgcn_global_load_lds(
        (const GLOBAL_AS void*)(A + (size_t)(bm + r0a) * lda + kt + k0a),
        (LDS_AS void*)(As + c0 * 8), 16, 0, 0);
    __builtin_amdgcn_global_load_lds(
        (const GLOBAL_AS void*)(A + (size_t)(bm + r1a) * lda + kt + k1a),
        (LDS_AS void*)(As + c1 * 8), 16, 0, 0);
    __builtin_amdgcn_global_load_lds(
        (const GLOBAL_AS void*)(Bt + (size_t)(bn + r0a) * ldb + kt + k0a),
        (LDS_AS void*)(Bs + c0 * 8), 16, 0, 0);
    __builtin_amdgcn_global_load_lds(
        (const GLOBAL_AS void*)(Bt + (size_t)(bn + r1a) * ldb + kt + k1a),
        (LDS_AS void*)(Bs + c1 * 8), 16, 0, 0);
    __syncthreads();

    short8 af[4], bfr[4];
#pragma unroll
    for (int i = 0; i < 4; ++i) {
      const int ra = wr + i * 16 + l15;
      af[i] = *(const short8*)(As + (ra * 4 + ((quad ^ ra) & 3)) * 8);
    }
#pragma unroll
    for (int j = 0; j < 4; ++j) {
      const int rb = wc + j * 16 + l15;
      bfr[j] = *(const short8*)(Bs + (rb * 4 + ((quad ^ rb) & 3)) * 8);
    }
#pragma unroll
    for (int i = 0; i < 4; ++i)
#pragma unroll
      for (int j = 0; j < 4; ++j)
        acc[i][j] = __builtin_amdgcn_mfma_f32_16x16x32_bf16(af[i], bfr[j], acc[i][j], 0, 0, 0);
    __syncthreads();
  }

  // epilogue — C/D layout: col = lane&15, row = quad*4 + reg
  const float scale = 0.044194173824159216f;  // 1/sqrt(512)
#pragma unroll
  for (int i = 0; i < 4; ++i) {
    const int rl = bm + wr + i * 16 + quad * 4;
#pragma unroll
    for (int r = 0; r < 4; ++r) {
      const int row = rl + r;
      float rsum = 0.f;
#pragma unroll
      for (int j = 0; j < 4; ++j) {
        const int col = bn + wc + j * 16 + l15;
        const float v = acc[i][j][r];
        if (MODE == 0) {
          Cb[(size_t)row * Ncols + col] = f2bf(v + bias[col]);
        } else {
          const float lg = ((row0 + row) == col) ? 0.f : v * scale;
          const unsigned short b = f2bf(__expf(lg));
          Cb[(size_t)row * Ncols + col] = b;
          rsum += bf2f(b);   // sum the ROUNDED value for num/denom consistency
        }
      }
      if (MODE == 1) {
        rsum += __shfl_xor(rsum, 1);
        rsum += __shfl_xor(rsum, 2);
        rsum += __shfl_xor(rsum, 4);
        rsum += __shfl_xor(rsum, 8);
        if (l15 == 0) atomicAdd(&lsum[row0 + row], rsum);
      }
    }
  }
}

// ---------------------------------------------------------------------------
// PV GEMM: O[m][n] = sum_k P[m][k] * HbT[n][k], 64x128 tile, split-K over z.
// DIRECT: writes out = v/l + H (single pass). Else writes fp32 partials.
// grid (ncols/128, rows/64, S); Kchunk = K/S.
// __launch_bounds__(256,8): 8 blocks/CU (12KB LDS x8 = 96KB, ~64-reg budget)
// ---------------------------------------------------------------------------
template <bool DIRECT>
__global__ __launch_bounds__(256, 8) void gemm_pv(
    const unsigned short* __restrict__ P,    // [rows][8192] bf16 (chunk base)
    const unsigned short* __restrict__ Bt,   // HbT [512][8192] bf16
    int Kchunk,
    const float* __restrict__ lvec,
    const float* __restrict__ Hres,
    int row0,
    float* __restrict__ outp,                // DIRECT: out; else partials base
    size_t partStride)                       // floats per partial buffer
{
  __shared__ unsigned short As[64 * 32];     // 4 KiB
  __shared__ unsigned short Bs[128 * 32];    // 8 KiB

  const int tid  = threadIdx.x;
  const int lane = tid & 63;
  const int wave = tid >> 6;
  const int wr   = (wave >> 1) * 32;
  const int wc   = (wave & 1) * 64;
  const int quad = lane >> 4;
  const int l15  = lane & 15;
  const int bm   = blockIdx.y * 64;
  const int bn   = blockIdx.x * 128;
  const int k0   = blockIdx.z * Kchunk;

  float* part = outp + (DIRECT ? 0 : (size_t)blockIdx.z * partStride);

  floatx4 acc[2][4];
#pragma unroll
  for (int i = 0; i < 2; ++i)
#pragma unroll
    for (int j = 0; j < 4; ++j)
      acc[i][j] = (floatx4){0.f, 0.f, 0.f, 0.f};

  const int rA = tid >> 2, kA = swz(tid) << 3;        // 256 chunks cover 64x32
  const int cB0 = tid, cB1 = tid + 256;               // 512 chunks cover 128x32
  const int rB0 = cB0 >> 2, kB0 = swz(cB0) << 3;
  const int rB1 = cB1 >> 2, kB1 = swz(cB1) << 3;

  for (int kt = k0; kt < k0 + Kchunk; kt += 32) {
    __builtin_amdgcn_global_load_lds(
        (const GLOBAL_AS void*)(P + (size_t)(bm + rA) * 8192 + kt + kA),
        (LDS_AS void*)(As + tid * 8), 16, 0, 0);
    __builtin_amdgcn_global_load_lds(
        (const GLOBAL_AS void*)(Bt + (size_t)(bn + rB0) * 8192 + kt + kB0),
        (LDS_AS void*)(Bs + cB0 * 8), 16, 0, 0);
    __builtin_amdgcn_global_load_lds(
        (const GLOBAL_AS void*)(Bt + (size_t)(bn + rB1) * 8192 + kt + kB1),
        (LDS_AS void*)(Bs + cB1 * 8), 16, 0, 0);
    __syncthreads();

    short8 af[2], bfr[4];
#pragma unroll
    for (int i = 0; i < 2; ++i) {
      const int ra = wr + i * 16 + l15;
      af[i] = *(const short8*)(As + (ra * 4 + ((quad ^ ra) & 3)) * 8);
    }
#pragma unroll
    for (int j = 0; j < 4; ++j) {
      const int rb = wc + j * 16 + l15;
      bfr[j] = *(const short8*)(Bs + (rb * 4 + ((quad ^ rb) & 3)) * 8);
    }
#pragma unroll
    for (int i = 0; i < 2; ++i)
#pragma unroll
      for (int j = 0; j < 4; ++j)
        acc[i][j] = __builtin_amdgcn_mfma_f32_16x16x32_bf16(af[i], bfr[j], acc[i][j], 0, 0, 0);
    __syncthreads();
  }

#pragma unroll
  for (int i = 0; i < 2; ++i) {
    const int rl = bm + wr + i * 16 + quad * 4;
#pragma unroll
    for (int j = 0; j < 4; ++j) {
      const int col = bn + wc + j * 16 + l15;
#pragma unroll
      for (int r = 0; r < 4; ++r) {
        const int row = rl + r;
        const float v = acc[i][j][r];
        if (DIRECT) {
          const int grow = row0 + row;
          part[(size_t)grow * 512 + col] =
              v / lvec[grow] + Hres[(size_t)grow * 512 + col];
        } else {
          part[(size_t)row * 512 + col] = v;
        }
      }
    }
  }
}

// combine: out = (sum_s partial_s) / l[row] + H
__global__ __launch_bounds__(256) void combine_kernel(
    const float* __restrict__ parts, size_t partStride, int S,
    const float* __restrict__ lvec, const float* __restrict__ Hres,
    float* __restrict__ out, int n4) {
  int i = blockIdx.x * 256 + threadIdx.x;
  if (i >= n4) return;
  float4 a = ((const float4*)parts)[i];
  for (int s = 1; s < S; ++s) {
    const float4 b = ((const float4*)(parts + (size_t)s * partStride))[i];
    a.x += b.x; a.y += b.y; a.z += b.z; a.w += b.w;
  }
  const int row = i >> 7;  // 128 float4 per 512-col row
  const float inv = 1.f / lvec[row];
  const float4 h = ((const float4*)Hres)[i];
  float4 o;
  o.x = a.x * inv + h.x;
  o.y = a.y * inv + h.y;
  o.z = a.z * inv + h.z;
  o.w = a.w * inv + h.w;
  ((float4*)out)[i] = o;
}

// ---------------------------------------------------------------------------
extern "C" void kernel_launch(void* const* d_in, const int* in_sizes, int n_in,
                              void* d_out, int out_size, void* d_ws, size_t ws_size,
                              hipStream_t stream) {
  const float* H  = (const float*)d_in[0];
  const float* Wq = (const float*)d_in[1];
  const float* bq = (const float*)d_in[2];
  const float* Wk = (const float*)d_in[3];
  const float* bk = (const float*)d_in[4];
  float* out = (float*)d_out;

  const int N = 8192, D = 512;

  char* ws = (char*)d_ws;
  size_t off = 0;
  auto alloc = [&](size_t bytes) { char* p = ws + off; off += bytes; return p; };
  unsigned short* Hb   = (unsigned short*)alloc((size_t)N * D * 2);       // 8 MB
  unsigned short* HbT  = (unsigned short*)alloc((size_t)N * D * 2);       // 8 MB
  unsigned short* QKb  = (unsigned short*)alloc((size_t)N * 2 * D * 2);   // 16.8 MB
  unsigned short* BqkT = (unsigned short*)alloc((size_t)2 * D * D * 2);   // 1 MB
  float* bqk = (float*)alloc((size_t)2 * D * 4);
  float* l   = (float*)alloc((size_t)N * 4);
  const size_t base = off;
  unsigned short* P = (unsigned short*)(ws + base);

  const size_t pBytes = (size_t)N * N * 2;               // 134 MB
  const size_t partBytes = (size_t)N * D * 4;            // 16.8 MB each
  const size_t partStride = (size_t)N * D;               // floats
  const size_t avail = (ws_size > base) ? (ws_size - base) : 0;

  int S = 0;  // 0 => must chunk P
  if (avail >= pBytes) {
    const size_t extra = avail - pBytes;
    S = (extra >= 4 * partBytes) ? 4 : (extra >= 2 * partBytes) ? 2 : 1;
  }
  float* parts = (float*)(ws + base + pBytes);

  // --- prep ---
  hipMemsetAsync(l, 0, (size_t)N * 4, stream);
  transpose_bf16_kernel<<<dim3(D / 64, N / 64), 256, 0, stream>>>(H, HbT, Hb, N, D);
  transpose_bf16_kernel<<<dim3(D / 64, D / 64), 256, 0, stream>>>(Wq, BqkT, nullptr, D, D);
  transpose_bf16_kernel<<<dim3(D / 64, D / 64), 256, 0, stream>>>(Wk, BqkT + (size_t)D * D, nullptr, D, D);
  pack_bias_kernel<<<dim3(4), 256, 0, stream>>>(bq, bk, bqk);

  // --- merged Q|K projection: QKb[8192][1024] = Hb @ [Wq|Wk] + [bq|bk] ---
  gemm_bt<0><<<dim3(2 * D / 128, N / 128), 256, 0, stream>>>(
      Hb, BqkT, 2 * D, D, D, D, bqk, nullptr, 0, QKb);

  if (S >= 1) {
    // scores: P = exp(diag0(Q K^T)*scale), fused row-sums into l
    gemm_bt<1><<<dim3(N / 128, N / 128), 256, 0, stream>>>(
        QKb, QKb + D, N, D, 2 * D, 2 * D, nullptr, l, 0, P);
    if (S == 1) {
      gemm_pv<true><<<dim3(D / 128, N / 64, 1), 256, 0, stream>>>(
          P, HbT, N, l, H, 0, out, 0);
    } else {
      gemm_pv<false><<<dim3(D / 128, N / 64, S), 256, 0, stream>>>(
          P, HbT, N / S, nullptr, nullptr, 0, parts, partStride);
      combine_kernel<<<dim3((N * D / 4 + 255) / 256), 256, 0, stream>>>(
          parts, partStride, S, l, H, out, N * D / 4);
    }
  } else {
    // ws too small for full P: chunk rows (direct PV per chunk)
    int maxRows = (int)(avail / ((size_t)N * 2));
    maxRows &= ~127;
    if (maxRows < 128) maxRows = 128;
    for (int r0 = 0; r0 < N; r0 += maxRows) {
      int rows = N - r0;
      if (rows > maxRows) rows = maxRows;
      gemm_bt<1><<<dim3(N / 128, rows / 128), 256, 0, stream>>>(
          QKb + (size_t)r0 * 2 * D, QKb + D, N, D, 2 * D, 2 * D, nullptr, l, r0, P);
      gemm_pv<true><<<dim3(D / 128, rows / 64, 1), 256, 0, stream>>>(
          P, HbT, N, l, H, r0, out, 0);
    }
  }
}